// Round 8
// baseline (2120.573 us; speedup 1.0000x reference)
//
#include <hip/hip_runtime.h>
#include <hip/hip_bf16.h>

#define NN 20000
#define EE 320000
#define HD 128   // hidden

typedef _Float16 half8 __attribute__((ext_vector_type(8)));
typedef _Float16 half4 __attribute__((ext_vector_type(4)));
typedef float floatx4 __attribute__((ext_vector_type(4)));

__device__ __forceinline__ float silu_f(float x){ return x / (1.f + __expf(-x)); }

__device__ __forceinline__ bool ei_is64(const int* __restrict__ ei){
  return (ei[1] | ei[3] | ei[5] | ei[7]) == 0;
}
__device__ __forceinline__ int ei_src(const int* __restrict__ ei, int e, bool is64){
  return is64 ? ei[2*(size_t)e] : ei[e];
}
__device__ __forceinline__ int ei_dst(const int* __restrict__ ei, int e, bool is64){
  return is64 ? ei[2*(size_t)EE + 2*(size_t)e] : ei[EE + e];
}

__global__ __launch_bounds__(256) void sentinel_kernel(float* __restrict__ out, int n, float val){
  int i = blockIdx.x*256 + threadIdx.x;
  if (i < n) out[i] = val;
}

// ---------------- W1 packing: MFMA B-fragment fp16 layout ----------------
// w1p[l*36864 + ((ks*8+cb)*64+lane)*8 + j] = W1[l][ks*32+(lane>>4)*8+j][cb*16+(lane&15)], 0 if k>=259
__global__ __launch_bounds__(256) void pack_w1_kernel(const float* __restrict__ w1,
                                                      _Float16* __restrict__ w1p){
  int idx = blockIdx.x*256 + threadIdx.x;      // 6*36864 = 221184 total
  int j    = idx & 7;
  int lane = (idx >> 3) & 63;
  int rest = idx >> 9;
  int cb   = rest & 7;
  int rest2= rest >> 3;
  int ks   = rest2 % 9;
  int l    = rest2 / 9;
  int k = ks*32 + (lane>>4)*8 + j;
  int n = cb*16 + (lane&15);
  float v = (k < 259) ? w1[(size_t)l*259*128 + (size_t)k*128 + n] : 0.f;
  w1p[idx] = (_Float16)v;
}

// ---------------- CSR build ----------------
__global__ __launch_bounds__(256) void count_kernel(const int* __restrict__ ei, int* __restrict__ cnt){
  int e = blockIdx.x*256 + threadIdx.x;   // EE/256 exact
  bool is64 = ei_is64(ei);
  atomicAdd(&cnt[ei_dst(ei, e, is64)], 1);
}

__global__ __launch_bounds__(1024) void scan_kernel(int* __restrict__ cntcur,
                                                    int* __restrict__ row_start,
                                                    float* __restrict__ invd){
  __shared__ int part[1024];
  const int t = threadIdx.x;
  const int base = t*20;
  int loc[20];
  int sum = 0;
  #pragma unroll
  for (int i=0;i<20;++i){
    int n = base+i;
    int v = (n < NN) ? cntcur[n] : 0;
    loc[i] = sum; sum += v;
  }
  part[t] = sum;
  __syncthreads();
  for (int off=1; off<1024; off<<=1){
    int v = (t >= off) ? part[t-off] : 0;
    __syncthreads();
    part[t] += v;
    __syncthreads();
  }
  int pre = (t > 0) ? part[t-1] : 0;
  #pragma unroll
  for (int i=0;i<20;++i){
    int n = base+i;
    if (n < NN){
      int rs = pre + loc[i];
      int deg = ((i<19)?loc[i+1]:sum) - loc[i];
      row_start[n] = rs;
      invd[n] = (deg > 0) ? 1.f/(float)deg : 0.f;
      cntcur[n] = rs;
    }
  }
  if (t == 1023) row_start[NN] = part[1023];
}

__global__ __launch_bounds__(256) void scatter_kernel(const int* __restrict__ ei,
                                                      const float* __restrict__ eattr,
                                                      int* __restrict__ cur,
                                                      int* __restrict__ src_s,
                                                      _Float16* __restrict__ ea_s){
  int e = blockIdx.x*256 + threadIdx.x;   // EE/256 exact
  bool is64 = ei_is64(ei);
  int s = ei_src(ei, e, is64);
  int d = ei_dst(ei, e, is64);
  int pos = atomicAdd(&cur[d], 1);
  src_s[pos] = s;
  half4 ea;
  ea[0] = (_Float16)eattr[(size_t)e*3+0];
  ea[1] = (_Float16)eattr[(size_t)e*3+1];
  ea[2] = (_Float16)eattr[(size_t)e*3+2];
  ea[3] = (_Float16)0.f;
  *(half4*)(ea_s + (size_t)pos*4) = ea;
}

// ---------------- encoder: x(N,14) -> h(N,128) fp32 + fp16 ----------------
__global__ __launch_bounds__(128) void encoder_kernel(
    const float* __restrict__ x, const float* __restrict__ w1, const float* __restrict__ b1,
    const float* __restrict__ w2, const float* __restrict__ b2,
    float* __restrict__ h, _Float16* __restrict__ hh)
{
  __shared__ float xs[16][14];
  __shared__ float s1[16][128];
  const int n0 = blockIdx.x*16;
  const int tid = threadIdx.x;
  for (int idx=tid; idx<224; idx+=128){
    int i = idx/14, k = idx%14;
    xs[i][k] = x[(size_t)(n0+i)*14 + k];
  }
  __syncthreads();
  const int o = tid;
  float acc[16];
  float bv = b1[o];
  #pragma unroll
  for (int i=0;i<16;++i) acc[i] = bv;
  for (int k=0;k<14;++k){
    float w = w1[k*128+o];
    #pragma unroll
    for (int i=0;i<16;++i) acc[i] += xs[i][k]*w;
  }
  #pragma unroll
  for (int i=0;i<16;++i) s1[i][o] = silu_f(acc[i]);
  __syncthreads();
  float bv2 = b2[o];
  #pragma unroll
  for (int i=0;i<16;++i) acc[i] = bv2;
  for (int k=0;k<128;k+=4){
    float w0=w2[(k+0)*128+o], w1v=w2[(k+1)*128+o], w2v=w2[(k+2)*128+o], w3v=w2[(k+3)*128+o];
    #pragma unroll
    for (int i=0;i<16;++i){
      float4 sv = *(const float4*)&s1[i][k];
      acc[i] += sv.x*w0 + sv.y*w1v + sv.z*w2v + sv.w*w3v;
    }
  }
  #pragma unroll
  for (int i=0;i<16;++i){
    size_t off = (size_t)(n0+i)*HD + o;
    h[off] = acc[i];
    hh[off] = (_Float16)acc[i];
  }
}

// ---------------- edge kernel (CSR v2): one node per wave ----------------
// - dst-half of GEMM hoisted out of the chunk loop (A rows identical -> dst_c[8])
// - chunk loop: 5 K-steps (src 4 + ea 1) x 8 col-blocks, B-frags from LDS (40KB)
// - __launch_bounds__(256,4): cap 128 VGPR -> 4 waves/SIMD; 4 blocks/CU * 40KB = 160KB LDS
__global__ __launch_bounds__(256, 4) void edge_csr_kernel(
    const _Float16* __restrict__ hh, const int* __restrict__ row_start,
    const int* __restrict__ src_s, const _Float16* __restrict__ ea_s,
    const _Float16* __restrict__ w1p, const float* __restrict__ b1,
    const float* __restrict__ invd, float* __restrict__ S)
{
  __shared__ _Float16 w1s[20480];   // ks 4..8 slice of w1p: 5*8*64*8 halfs = 40,960 B
  const int tid = threadIdx.x;
  {
    const half8* gsrc = (const half8*)(w1p + 16384);  // ks=4 starts at 4*8*64*8
    half8* ldst = (half8*)w1s;
    #pragma unroll
    for (int i = 0; i < 10; ++i)
      ldst[tid + i*256] = gsrc[tid + i*256];
  }
  __syncthreads();

  const int wv = tid >> 6;
  const int ln = tid & 63;
  const int q  = ln >> 4;
  const int m  = ln & 15;
  const int n  = blockIdx.x*4 + wv;     // grid = NN/4 = 5000, exact
  const int rs = row_start[n], re = row_start[n+1];
  const int nch = (re - rs + 15) >> 4;
  const int clampi = (re > rs) ? re - 1 : rs;

  float bv[8];
  #pragma unroll
  for (int cb=0;cb<8;++cb) bv[cb] = b1[cb*16 + m];

  // dst contribution (chunk-invariant): 32 MFMAs, all 16 A-rows = h[n] -> rows identical
  float dst_c[8];
  {
    floatx4 accd[8];
    #pragma unroll
    for (int cb=0;cb<8;++cb) accd[cb] = (floatx4){0.f,0.f,0.f,0.f};
    #pragma unroll
    for (int ks=0; ks<4; ++ks){
      half8 a = *(const half8*)(hh + (size_t)n*HD + ks*32 + q*8);
      const _Float16* wb = w1p + (size_t)(ks*8*64 + ln)*8;   // global; L1-hot
      #pragma unroll
      for (int cb=0; cb<8; ++cb){
        half8 b = *(const half8*)(wb + cb*512);
        accd[cb] = __builtin_amdgcn_mfma_f32_16x16x32_f16(a, b, accd[cb], 0,0,0);
      }
    }
    #pragma unroll
    for (int cb=0;cb<8;++cb) dst_c[cb] = accd[cb][0];
  }

  float pl[8];
  #pragma unroll
  for (int cb=0;cb<8;++cb) pl[cb] = 0.f;

  for (int c = 0; c < nch; ++c){
    int p  = rs + c*16 + m;
    int pc = p < clampi ? p : clampi;
    const int s = src_s[pc];

    floatx4 acc[8];
    #pragma unroll
    for (int cb=0;cb<8;++cb) acc[cb] = (floatx4){0.f,0.f,0.f,0.f};

    // src phases: global k 128..255 -> hh[s] k 0..127 ; LDS ks_local 0..3
    #pragma unroll
    for (int ks=0; ks<4; ++ks){
      half8 a = *(const half8*)(hh + (size_t)s*HD + ks*32 + q*8);
      const _Float16* wb = w1s + (size_t)(ks*8)*512 + (size_t)ln*8;
      #pragma unroll
      for (int cb=0; cb<8; ++cb){
        half8 b = *(const half8*)(wb + cb*512);
        acc[cb] = __builtin_amdgcn_mfma_f32_16x16x32_f16(a, b, acc[cb], 0,0,0);
      }
    }
    // ea tail: LDS ks_local 4
    {
      half8 a;
      #pragma unroll
      for (int j=0;j<8;++j) a[j] = (_Float16)0.f;
      if (q == 0){
        half4 e0 = *(const half4*)(ea_s + (size_t)pc*4);
        a[0]=e0[0]; a[1]=e0[1]; a[2]=e0[2]; a[3]=e0[3];
      }
      const _Float16* wb = w1s + (size_t)(4*8)*512 + (size_t)ln*8;
      #pragma unroll
      for (int cb=0; cb<8; ++cb){
        half8 b = *(const half8*)(wb + cb*512);
        acc[cb] = __builtin_amdgcn_mfma_f32_16x16x32_f16(a, b, acc[cb], 0,0,0);
      }
    }
    // epilogue: C row = q*4+r (edge), col = cb*16+m; add dst part + bias, silu, masked sum
    #pragma unroll
    for (int cb=0; cb<8; ++cb){
      #pragma unroll
      for (int r=0;r<4;++r){
        if (rs + c*16 + q*4 + r < re)
          pl[cb] += silu_f(acc[cb][r] + dst_c[cb] + bv[cb]);
      }
    }
  }

  // cross-quad reduce: lanes m,m+16,m+32,m+48 hold the 4 row-groups of col cb*16+m
  #pragma unroll
  for (int cb=0; cb<8; ++cb){
    pl[cb] += __shfl_xor(pl[cb], 16);
    pl[cb] += __shfl_xor(pl[cb], 32);
  }
  const float iv = invd[n];
  S[(size_t)n*HD + q*32 + m]      = pl[2*q]   * iv;
  S[(size_t)n*HD + q*32 + 16 + m] = pl[2*q+1] * iv;
}

// ---------------- node update: h += S·W2 + b2 (S already the mean), refresh hh ----------------
__global__ __launch_bounds__(128) void node_kernel(
    const float* __restrict__ w2, const float* __restrict__ b2,
    const float* __restrict__ S, const float* __restrict__ invd,
    float* __restrict__ h, _Float16* __restrict__ hh)
{
  __shared__ float t[16][128];
  const int n0 = blockIdx.x*16;
  const int tid = threadIdx.x;
  for (int idx=tid; idx<2048; idx+=128){
    int i = idx >> 7, k = idx & 127;
    t[i][k] = S[(size_t)(n0+i)*HD + k];
  }
  __syncthreads();
  const int o = tid;
  float acc[16];
  const float bv = b2[o];
  #pragma unroll
  for (int i=0;i<16;++i) acc[i] = (invd[n0+i] > 0.f) ? bv : 0.f;
  for (int k=0;k<128;k+=4){
    float w0 = w2[(k+0)*128+o];
    float w1v= w2[(k+1)*128+o];
    float w2v= w2[(k+2)*128+o];
    float w3v= w2[(k+3)*128+o];
    #pragma unroll
    for (int i=0;i<16;++i){
      float4 tv = *(const float4*)&t[i][k];
      acc[i] += tv.x*w0 + tv.y*w1v + tv.z*w2v + tv.w*w3v;
    }
  }
  #pragma unroll
  for (int i=0;i<16;++i){
    size_t off = (size_t)(n0+i)*HD + o;
    float hv = h[off] + acc[i];
    h[off] = hv;
    hh[off] = (_Float16)hv;
  }
}

// ---------------- decoder: 128 ->(silu) 128 ->(silu) 64 -> 9 ----------------
__global__ __launch_bounds__(128) void decoder_kernel(
    const float* __restrict__ h,
    const float* __restrict__ w1, const float* __restrict__ b1,
    const float* __restrict__ w2, const float* __restrict__ b2,
    const float* __restrict__ w3, const float* __restrict__ b3,
    float* __restrict__ out)
{
  __shared__ float ht[16][128];
  __shared__ float s1[16][128];
  __shared__ float s2[16][64];
  const int n0 = blockIdx.x*16;
  const int tid = threadIdx.x;
  for (int idx=tid; idx<2048; idx+=128){
    int i = idx>>7, k = idx&127;
    ht[i][k] = h[(size_t)(n0+i)*HD + k];
  }
  __syncthreads();
  {
    const int o = tid;
    float acc[16];
    float bv = b1[o];
    #pragma unroll
    for (int i=0;i<16;++i) acc[i] = bv;
    for (int k=0;k<128;k+=4){
      float w0=w1[(k+0)*128+o], w1v=w1[(k+1)*128+o], w2v=w1[(k+2)*128+o], w3v=w1[(k+3)*128+o];
      #pragma unroll
      for (int i=0;i<16;++i){
        float4 hv = *(const float4*)&ht[i][k];
        acc[i] += hv.x*w0 + hv.y*w1v + hv.z*w2v + hv.w*w3v;
      }
    }
    #pragma unroll
    for (int i=0;i<16;++i) s1[i][o] = silu_f(acc[i]);
  }
  __syncthreads();
  {
    const int o = tid & 63;
    const int hf = tid >> 6;
    float acc[8];
    float bv = b2[o];
    #pragma unroll
    for (int i=0;i<8;++i) acc[i] = bv;
    for (int k=0;k<128;k+=4){
      float w0=w2[(k+0)*64+o], w1v=w2[(k+1)*64+o], w2v=w2[(k+2)*64+o], w3v=w2[(k+3)*64+o];
      #pragma unroll
      for (int i=0;i<8;++i){
        float4 sv = *(const float4*)&s1[hf*8+i][k];
        acc[i] += sv.x*w0 + sv.y*w1v + sv.z*w2v + sv.w*w3v;
      }
    }
    #pragma unroll
    for (int i=0;i<8;++i) s2[hf*8+i][o] = silu_f(acc[i]);
  }
  __syncthreads();
  // loop (NOT "if (tid<144)") — the r1-r5 bug
  for (int idx = tid; idx < 144; idx += 128){
    int i = idx/9, oo = idx%9;
    float a = b3[oo];
    #pragma unroll 8
    for (int k=0;k<64;++k) a += s2[i][k]*w3[k*9+oo];
    out[(size_t)(n0+i)*9 + oo] = a;
  }
}

// ---------------- workspace layout (30,204,352 B) ----------------
constexpr size_t OFF_W1P  = 0;                         // 442,368 -> pad
constexpr size_t OFF_H    = 524288;                    // +10,240,000
constexpr size_t OFF_HH   = OFF_H   + 10240000;        // +5,120,000
constexpr size_t OFF_S    = OFF_HH  + 5120000;         // +10,240,000
constexpr size_t OFF_INVD = OFF_S   + 10240000;        // +80,000
constexpr size_t OFF_RS   = OFF_INVD + 80000;          // row_start: (NN+1)*4 -> 80,064
constexpr size_t OFF_CUR  = OFF_RS  + 80064;           // cnt/cursor +80,000
constexpr size_t OFF_SRC  = OFF_CUR + 80000;           // src_s: EE*4 = 1,280,000
constexpr size_t OFF_EA   = OFF_SRC + 1280000;         // ea_s: EE*4*2 = 2,560,000
constexpr size_t WS_NEEDED= OFF_EA  + 2560000;

extern "C" void kernel_launch(void* const* d_in, const int* in_sizes, int n_in,
                              void* d_out, int out_size, void* d_ws, size_t ws_size,
                              hipStream_t stream)
{
  float* out = (float*)d_out;
  const int nout_blk = (out_size + 255)/256;

  static const int EXP_SIZES[17] = {280000,640000,960000,1792,128,16384,128,
                                    198912,768,98304,768,16384,128,8192,64,576,9};
  if (n_in != 17){
    sentinel_kernel<<<nout_blk, 256, 0, stream>>>(out, out_size, 2.0e7f + (float)n_in*1.0e3f);
    return;
  }
  for (int i = 0; i < 17; ++i){
    if (in_sizes[i] != EXP_SIZES[i]){
      int sz = in_sizes[i] < 99999 ? in_sizes[i] : 99999;
      sentinel_kernel<<<nout_blk, 256, 0, stream>>>(out, out_size,
          1.0e7f + (float)i*1.0e5f + (float)sz);
      return;
    }
  }
  if (ws_size < WS_NEEDED){
    sentinel_kernel<<<nout_blk, 256, 0, stream>>>(out, out_size, 1.0e6f);
    return;
  }

  const float* x       = (const float*)d_in[0];
  const int*   ei      = (const int*)  d_in[1];
  const float* eattr   = (const float*)d_in[2];
  const float* enc_w1  = (const float*)d_in[3];
  const float* enc_b1  = (const float*)d_in[4];
  const float* enc_w2  = (const float*)d_in[5];
  const float* enc_b2  = (const float*)d_in[6];
  const float* conv_w1 = (const float*)d_in[7];
  const float* conv_b1 = (const float*)d_in[8];
  const float* conv_w2 = (const float*)d_in[9];
  const float* conv_b2 = (const float*)d_in[10];
  const float* dec_w1  = (const float*)d_in[11];
  const float* dec_b1  = (const float*)d_in[12];
  const float* dec_w2  = (const float*)d_in[13];
  const float* dec_b2  = (const float*)d_in[14];
  const float* dec_w3  = (const float*)d_in[15];
  const float* dec_b3  = (const float*)d_in[16];

  char* ws = (char*)d_ws;
  _Float16* w1p   = (_Float16*)(ws + OFF_W1P);
  float*    h     = (float*)   (ws + OFF_H);
  _Float16* hh    = (_Float16*)(ws + OFF_HH);
  float*    S     = (float*)   (ws + OFF_S);
  float*    invd  = (float*)   (ws + OFF_INVD);
  int*      rstart= (int*)     (ws + OFF_RS);
  int*      cur   = (int*)     (ws + OFF_CUR);
  int*      src_s = (int*)     (ws + OFF_SRC);
  _Float16* ea_s  = (_Float16*)(ws + OFF_EA);

  hipMemsetAsync(cur, 0, (size_t)NN*sizeof(int), stream);

  pack_w1_kernel<<<864, 256, 0, stream>>>(conv_w1, w1p);
  count_kernel<<<EE/256, 256, 0, stream>>>(ei, cur);
  scan_kernel<<<1, 1024, 0, stream>>>(cur, rstart, invd);
  scatter_kernel<<<EE/256, 256, 0, stream>>>(ei, eattr, cur, src_s, ea_s);
  encoder_kernel<<<NN/16, 128, 0, stream>>>(x, enc_w1, enc_b1, enc_w2, enc_b2, h, hh);
  for (int l=0; l<6; ++l){
    edge_csr_kernel<<<NN/4, 256, 0, stream>>>(hh, rstart, src_s, ea_s,
                                              w1p + (size_t)l*36864,
                                              conv_b1 + (size_t)l*128, invd, S);
    node_kernel<<<NN/16, 128, 0, stream>>>(conv_w2 + (size_t)l*16384,
                                           conv_b2 + (size_t)l*128,
                                           S, invd, h, hh);
  }
  decoder_kernel<<<NN/16, 128, 0, stream>>>(h, dec_w1, dec_b1, dec_w2, dec_b2,
                                            dec_w3, dec_b3, out);
}

// Round 9
// 756.279 us; speedup vs baseline: 2.8040x; 2.8040x over previous
//
#include <hip/hip_runtime.h>
#include <hip/hip_bf16.h>

#define NN 20000
#define EE 320000
#define HD 128   // hidden

typedef _Float16 half8 __attribute__((ext_vector_type(8)));
typedef _Float16 half4 __attribute__((ext_vector_type(4)));
typedef _Float16 half2v __attribute__((ext_vector_type(2)));

__device__ __forceinline__ float silu_f(float x){ return x / (1.f + __expf(-x)); }

__device__ __forceinline__ bool ei_is64(const int* __restrict__ ei){
  return (ei[1] | ei[3] | ei[5] | ei[7]) == 0;
}
__device__ __forceinline__ int ei_src(const int* __restrict__ ei, int e, bool is64){
  return is64 ? ei[2*(size_t)e] : ei[e];
}
__device__ __forceinline__ int ei_dst(const int* __restrict__ ei, int e, bool is64){
  return is64 ? ei[2*(size_t)EE + 2*(size_t)e] : ei[EE + e];
}

__global__ __launch_bounds__(256) void sentinel_kernel(float* __restrict__ out, int n, float val){
  int i = blockIdx.x*256 + threadIdx.x;
  if (i < n) out[i] = val;
}

// ---------------- CSR build ----------------
__global__ __launch_bounds__(256) void count_kernel(const int* __restrict__ ei, int* __restrict__ cnt){
  int e = blockIdx.x*256 + threadIdx.x;   // EE/256 exact
  bool is64 = ei_is64(ei);
  atomicAdd(&cnt[ei_dst(ei, e, is64)], 1);
}

__global__ __launch_bounds__(1024) void scan_kernel(int* __restrict__ cntcur,
                                                    int* __restrict__ row_start,
                                                    float* __restrict__ invd){
  __shared__ int part[1024];
  const int t = threadIdx.x;
  const int base = t*20;
  int loc[20];
  int sum = 0;
  #pragma unroll
  for (int i=0;i<20;++i){
    int n = base+i;
    int v = (n < NN) ? cntcur[n] : 0;
    loc[i] = sum; sum += v;
  }
  part[t] = sum;
  __syncthreads();
  for (int off=1; off<1024; off<<=1){
    int v = (t >= off) ? part[t-off] : 0;
    __syncthreads();
    part[t] += v;
    __syncthreads();
  }
  int pre = (t > 0) ? part[t-1] : 0;
  #pragma unroll
  for (int i=0;i<20;++i){
    int n = base+i;
    if (n < NN){
      int rs = pre + loc[i];
      int deg = ((i<19)?loc[i+1]:sum) - loc[i];
      row_start[n] = rs;
      invd[n] = (deg > 0) ? 1.f/(float)deg : 0.f;
      cntcur[n] = rs;
    }
  }
  if (t == 1023) row_start[NN] = part[1023];
}

__global__ __launch_bounds__(256) void scatter_kernel(const int* __restrict__ ei,
                                                      const float* __restrict__ eattr,
                                                      int* __restrict__ cur,
                                                      int* __restrict__ src_s,
                                                      _Float16* __restrict__ ea_s){
  int e = blockIdx.x*256 + threadIdx.x;   // EE/256 exact
  bool is64 = ei_is64(ei);
  int s = ei_src(ei, e, is64);
  int d = ei_dst(ei, e, is64);
  int pos = atomicAdd(&cur[d], 1);
  src_s[pos] = s;
  half4 ea;
  ea[0] = (_Float16)eattr[(size_t)e*3+0];
  ea[1] = (_Float16)eattr[(size_t)e*3+1];
  ea[2] = (_Float16)eattr[(size_t)e*3+2];
  ea[3] = (_Float16)0.f;
  *(half4*)(ea_s + (size_t)pos*4) = ea;
}

// ---------------- encoder: x(N,14) -> h(N,128) fp32 ----------------
__global__ __launch_bounds__(128) void encoder_kernel(
    const float* __restrict__ x, const float* __restrict__ w1, const float* __restrict__ b1,
    const float* __restrict__ w2, const float* __restrict__ b2,
    float* __restrict__ h)
{
  __shared__ float xs[16][14];
  __shared__ float s1[16][128];
  const int n0 = blockIdx.x*16;
  const int tid = threadIdx.x;
  for (int idx=tid; idx<224; idx+=128){
    int i = idx/14, k = idx%14;
    xs[i][k] = x[(size_t)(n0+i)*14 + k];
  }
  __syncthreads();
  const int o = tid;
  float acc[16];
  float bv = b1[o];
  #pragma unroll
  for (int i=0;i<16;++i) acc[i] = bv;
  for (int k=0;k<14;++k){
    float w = w1[k*128+o];
    #pragma unroll
    for (int i=0;i<16;++i) acc[i] += xs[i][k]*w;
  }
  #pragma unroll
  for (int i=0;i<16;++i) s1[i][o] = silu_f(acc[i]);
  __syncthreads();
  float bv2 = b2[o];
  #pragma unroll
  for (int i=0;i<16;++i) acc[i] = bv2;
  for (int k=0;k<128;k+=4){
    float w0=w2[(k+0)*128+o], w1v=w2[(k+1)*128+o], w2v=w2[(k+2)*128+o], w3v=w2[(k+3)*128+o];
    #pragma unroll
    for (int i=0;i<16;++i){
      float4 sv = *(const float4*)&s1[i][k];
      acc[i] += sv.x*w0 + sv.y*w1v + sv.z*w2v + sv.w*w3v;
    }
  }
  #pragma unroll
  for (int i=0;i<16;++i) h[(size_t)(n0+i)*HD + o] = acc[i];
}

// ---------------- proj: UV(N,256) = [h·W1d + b1 | h·W1s], fp32 compute, fp16 store ----------------
// W1 rows 0..127 -> U (dst part, +b1), rows 128..255 -> V (src part). 16 nodes/block, 256 thr.
__global__ __launch_bounds__(256) void proj_kernel(
    const float* __restrict__ h, const float* __restrict__ cw1,
    const float* __restrict__ b1, _Float16* __restrict__ UV)
{
  __shared__ __align__(16) float hs[16][128];
  const int n0 = blockIdx.x*16;
  const int tid = threadIdx.x;
  for (int idx = tid; idx < 2048; idx += 256){
    int i = idx >> 7, k = idx & 127;
    hs[i][k] = h[(size_t)(n0+i)*HD + k];
  }
  __syncthreads();
  const int c = tid;     // 0..255
  const float* wp = cw1 + (c < 128 ? c : (16384 + c - 128));
  float acc[16];
  const float binit = (c < 128) ? b1[c] : 0.f;
  #pragma unroll
  for (int i=0;i<16;++i) acc[i] = binit;
  for (int k=0;k<128;k+=4){
    float w0 = wp[(size_t)(k+0)*128];
    float w1v= wp[(size_t)(k+1)*128];
    float w2v= wp[(size_t)(k+2)*128];
    float w3v= wp[(size_t)(k+3)*128];
    #pragma unroll
    for (int i=0;i<16;++i){
      float4 hv = *(const float4*)&hs[i][k];
      acc[i] += hv.x*w0 + hv.y*w1v + hv.z*w2v + hv.w*w3v;
    }
  }
  #pragma unroll
  for (int i=0;i<16;++i)
    UV[(size_t)(n0+i)*256 + c] = (_Float16)acc[i];
}

// ---------------- edge_agg: per-node mean of silu(U[n] + V[src] + ea·W1e) ----------------
// one wave per node (4 nodes/block); lane handles channels {2l, 2l+1}.
// V gather = one coalesced 256 B row per edge. No MFMA, ~30 VGPRs -> high occupancy.
__global__ __launch_bounds__(256) void edge_agg_kernel(
    const _Float16* __restrict__ UV, const int* __restrict__ row_start,
    const int* __restrict__ src_s, const _Float16* __restrict__ ea_s,
    const float* __restrict__ w1e,      // conv_w1 + l*33152 + 32768 (3 rows x 128)
    const float* __restrict__ invd, _Float16* __restrict__ S)
{
  const int tid = threadIdx.x;
  const int wv  = __builtin_amdgcn_readfirstlane(tid >> 6);  // wave-uniform
  const int ln  = tid & 63;
  const int n   = blockIdx.x*4 + wv;   // grid NN/4 = 5000 exact
  const int c0  = ln*2;

  const float2 wc0 = *(const float2*)(w1e +   0 + c0);
  const float2 wc1 = *(const float2*)(w1e + 128 + c0);
  const float2 wc2 = *(const float2*)(w1e + 256 + c0);

  half2v uvp = *(const half2v*)(UV + (size_t)n*256 + c0);
  const float u0 = (float)uvp[0], u1 = (float)uvp[1];

  const int rs = row_start[n], re = row_start[n+1];
  float a0 = 0.f, a1 = 0.f;
  if (re > rs){
    int s = src_s[rs];
    half4 ea = *(const half4*)(ea_s + (size_t)rs*4);
    half2v v = *(const half2v*)(UV + (size_t)s*256 + 128 + c0);
    for (int e = rs+1; e <= re; ++e){
      int s2 = 0; half4 ea2 = {}; half2v v2 = {};
      if (e < re){                     // prefetch next edge
        s2  = src_s[e];
        ea2 = *(const half4*)(ea_s + (size_t)e*4);
        v2  = *(const half2v*)(UV + (size_t)s2*256 + 128 + c0);
      }
      const float e0 = (float)ea[0], e1 = (float)ea[1], e2 = (float)ea[2];
      float p0 = u0 + (float)v[0] + e0*wc0.x + e1*wc1.x + e2*wc2.x;
      float p1 = u1 + (float)v[1] + e0*wc0.y + e1*wc1.y + e2*wc2.y;
      a0 += silu_f(p0);
      a1 += silu_f(p1);
      s = s2; ea = ea2; v = v2;
    }
  }
  const float iv = invd[n];
  half2v outv; outv[0] = (_Float16)(a0*iv); outv[1] = (_Float16)(a1*iv);
  *(half2v*)(S + (size_t)n*HD + c0) = outv;
}

// ---------------- node update: h += S·W2 + b2 (S fp16 mean), 16 nodes/block ----------------
__global__ __launch_bounds__(128) void node_kernel(
    const float* __restrict__ w2, const float* __restrict__ b2,
    const _Float16* __restrict__ S, const float* __restrict__ invd,
    float* __restrict__ h)
{
  __shared__ float t[16][128];
  const int n0 = blockIdx.x*16;
  const int tid = threadIdx.x;
  for (int idx=tid; idx<2048; idx+=128){
    int i = idx >> 7, k = idx & 127;
    t[i][k] = (float)S[(size_t)(n0+i)*HD + k];
  }
  __syncthreads();
  const int o = tid;
  float acc[16];
  const float bv = b2[o];
  #pragma unroll
  for (int i=0;i<16;++i) acc[i] = (invd[n0+i] > 0.f) ? bv : 0.f;
  for (int k=0;k<128;k+=4){
    float w0 = w2[(k+0)*128+o];
    float w1v= w2[(k+1)*128+o];
    float w2v= w2[(k+2)*128+o];
    float w3v= w2[(k+3)*128+o];
    #pragma unroll
    for (int i=0;i<16;++i){
      float4 tv = *(const float4*)&t[i][k];
      acc[i] += tv.x*w0 + tv.y*w1v + tv.z*w2v + tv.w*w3v;
    }
  }
  #pragma unroll
  for (int i=0;i<16;++i){
    size_t off = (size_t)(n0+i)*HD + o;
    h[off] = h[off] + acc[i];
  }
}

// ---------------- decoder: 128 ->(silu) 128 ->(silu) 64 -> 9 ----------------
__global__ __launch_bounds__(128) void decoder_kernel(
    const float* __restrict__ h,
    const float* __restrict__ w1, const float* __restrict__ b1,
    const float* __restrict__ w2, const float* __restrict__ b2,
    const float* __restrict__ w3, const float* __restrict__ b3,
    float* __restrict__ out)
{
  __shared__ float ht[16][128];
  __shared__ float s1[16][128];
  __shared__ float s2[16][64];
  const int n0 = blockIdx.x*16;
  const int tid = threadIdx.x;
  for (int idx=tid; idx<2048; idx+=128){
    int i = idx>>7, k = idx&127;
    ht[i][k] = h[(size_t)(n0+i)*HD + k];
  }
  __syncthreads();
  {
    const int o = tid;
    float acc[16];
    float bv = b1[o];
    #pragma unroll
    for (int i=0;i<16;++i) acc[i] = bv;
    for (int k=0;k<128;k+=4){
      float w0=w1[(k+0)*128+o], w1v=w1[(k+1)*128+o], w2v=w1[(k+2)*128+o], w3v=w1[(k+3)*128+o];
      #pragma unroll
      for (int i=0;i<16;++i){
        float4 hv = *(const float4*)&ht[i][k];
        acc[i] += hv.x*w0 + hv.y*w1v + hv.z*w2v + hv.w*w3v;
      }
    }
    #pragma unroll
    for (int i=0;i<16;++i) s1[i][o] = silu_f(acc[i]);
  }
  __syncthreads();
  {
    const int o = tid & 63;
    const int hf = tid >> 6;
    float acc[8];
    float bv = b2[o];
    #pragma unroll
    for (int i=0;i<8;++i) acc[i] = bv;
    for (int k=0;k<128;k+=4){
      float w0=w2[(k+0)*64+o], w1v=w2[(k+1)*64+o], w2v=w2[(k+2)*64+o], w3v=w2[(k+3)*64+o];
      #pragma unroll
      for (int i=0;i<8;++i){
        float4 sv = *(const float4*)&s1[hf*8+i][k];
        acc[i] += sv.x*w0 + sv.y*w1v + sv.z*w2v + sv.w*w3v;
      }
    }
    #pragma unroll
    for (int i=0;i<8;++i) s2[hf*8+i][o] = silu_f(acc[i]);
  }
  __syncthreads();
  for (int idx = tid; idx < 144; idx += 128){   // loop, NOT "if" — the r1-r5 bug
    int i = idx/9, oo = idx%9;
    float a = b3[oo];
    #pragma unroll 8
    for (int k=0;k<64;++k) a += s2[i][k]*w3[k*9+oo];
    out[(size_t)(n0+i)*9 + oo] = a;
  }
}

// ---------------- workspace layout (29,680,064 B; r7's 30.2 MB fit) ----------------
constexpr size_t OFF_H    = 0;                         // 10,240,000
constexpr size_t OFF_UV   = 10240000;                  // N*256*2 = 10,240,000
constexpr size_t OFF_S    = 20480000;                  // N*128*2 =  5,120,000 (fp16)
constexpr size_t OFF_INVD = 25600000;                  // 80,000
constexpr size_t OFF_RS   = 25680000;                  // 80,064
constexpr size_t OFF_CUR  = 25760064;                  // 80,000
constexpr size_t OFF_SRC  = 25840064;                  // 1,280,000
constexpr size_t OFF_EA   = 27120064;                  // 2,560,000
constexpr size_t WS_NEEDED= 29680064;

extern "C" void kernel_launch(void* const* d_in, const int* in_sizes, int n_in,
                              void* d_out, int out_size, void* d_ws, size_t ws_size,
                              hipStream_t stream)
{
  float* out = (float*)d_out;
  const int nout_blk = (out_size + 255)/256;

  static const int EXP_SIZES[17] = {280000,640000,960000,1792,128,16384,128,
                                    198912,768,98304,768,16384,128,8192,64,576,9};
  if (n_in != 17){
    sentinel_kernel<<<nout_blk, 256, 0, stream>>>(out, out_size, 2.0e7f + (float)n_in*1.0e3f);
    return;
  }
  for (int i = 0; i < 17; ++i){
    if (in_sizes[i] != EXP_SIZES[i]){
      int sz = in_sizes[i] < 99999 ? in_sizes[i] : 99999;
      sentinel_kernel<<<nout_blk, 256, 0, stream>>>(out, out_size,
          1.0e7f + (float)i*1.0e5f + (float)sz);
      return;
    }
  }
  if (ws_size < WS_NEEDED){
    sentinel_kernel<<<nout_blk, 256, 0, stream>>>(out, out_size, 1.0e6f);
    return;
  }

  const float* x       = (const float*)d_in[0];
  const int*   ei      = (const int*)  d_in[1];
  const float* eattr   = (const float*)d_in[2];
  const float* enc_w1  = (const float*)d_in[3];
  const float* enc_b1  = (const float*)d_in[4];
  const float* enc_w2  = (const float*)d_in[5];
  const float* enc_b2  = (const float*)d_in[6];
  const float* conv_w1 = (const float*)d_in[7];
  const float* conv_b1 = (const float*)d_in[8];
  const float* conv_w2 = (const float*)d_in[9];
  const float* conv_b2 = (const float*)d_in[10];
  const float* dec_w1  = (const float*)d_in[11];
  const float* dec_b1  = (const float*)d_in[12];
  const float* dec_w2  = (const float*)d_in[13];
  const float* dec_b2  = (const float*)d_in[14];
  const float* dec_w3  = (const float*)d_in[15];
  const float* dec_b3  = (const float*)d_in[16];

  char* ws = (char*)d_ws;
  float*    h     = (float*)   (ws + OFF_H);
  _Float16* UV    = (_Float16*)(ws + OFF_UV);
  _Float16* S     = (_Float16*)(ws + OFF_S);
  float*    invd  = (float*)   (ws + OFF_INVD);
  int*      rstart= (int*)     (ws + OFF_RS);
  int*      cur   = (int*)     (ws + OFF_CUR);
  int*      src_s = (int*)     (ws + OFF_SRC);
  _Float16* ea_s  = (_Float16*)(ws + OFF_EA);

  hipMemsetAsync(cur, 0, (size_t)NN*sizeof(int), stream);

  count_kernel<<<EE/256, 256, 0, stream>>>(ei, cur);
  scan_kernel<<<1, 1024, 0, stream>>>(cur, rstart, invd);
  scatter_kernel<<<EE/256, 256, 0, stream>>>(ei, eattr, cur, src_s, ea_s);
  encoder_kernel<<<NN/16, 128, 0, stream>>>(x, enc_w1, enc_b1, enc_w2, enc_b2, h);
  for (int l=0; l<6; ++l){
    proj_kernel<<<NN/16, 256, 0, stream>>>(h, conv_w1 + (size_t)l*33152,
                                           conv_b1 + (size_t)l*128, UV);
    edge_agg_kernel<<<NN/4, 256, 0, stream>>>(UV, rstart, src_s, ea_s,
                                              conv_w1 + (size_t)l*33152 + 32768,
                                              invd, S);
    node_kernel<<<NN/16, 128, 0, stream>>>(conv_w2 + (size_t)l*16384,
                                           conv_b2 + (size_t)l*128,
                                           S, invd, h);
  }
  decoder_kernel<<<NN/16, 128, 0, stream>>>(h, dec_w1, dec_b1, dec_w2, dec_b2,
                                            dec_w3, dec_b3, out);
}

// Round 10
// 561.071 us; speedup vs baseline: 3.7795x; 1.3479x over previous
//
#include <hip/hip_runtime.h>
#include <hip/hip_bf16.h>

#define NN 20000
#define EE 320000
#define HD 128   // hidden

typedef _Float16 half8 __attribute__((ext_vector_type(8)));
typedef _Float16 half4 __attribute__((ext_vector_type(4)));
typedef _Float16 half2v __attribute__((ext_vector_type(2)));
typedef float floatx4 __attribute__((ext_vector_type(4)));

__device__ __forceinline__ float silu_f(float x){ return x / (1.f + __expf(-x)); }

__device__ __forceinline__ bool ei_is64(const int* __restrict__ ei){
  return (ei[1] | ei[3] | ei[5] | ei[7]) == 0;
}
__device__ __forceinline__ int ei_src(const int* __restrict__ ei, int e, bool is64){
  return is64 ? ei[2*(size_t)e] : ei[e];
}
__device__ __forceinline__ int ei_dst(const int* __restrict__ ei, int e, bool is64){
  return is64 ? ei[2*(size_t)EE + 2*(size_t)e] : ei[EE + e];
}

__global__ __launch_bounds__(256) void sentinel_kernel(float* __restrict__ out, int n, float val){
  int i = blockIdx.x*256 + threadIdx.x;
  if (i < n) out[i] = val;
}

// ---------------- weight packing: MFMA B-fragment layouts ----------------
// proj weights W~[k][c] (k<128, c<256): c<128 -> conv_w1[k][c]; else conv_w1[128+k][c-128]
// w1p[l][ks][cb(16)][ln][j] ; 6*4*16*64*8 = 196608 halfs
__global__ __launch_bounds__(256) void pack_w1p_kernel(const float* __restrict__ cw1,
                                                       _Float16* __restrict__ w1p){
  int idx = blockIdx.x*256 + threadIdx.x;   // 768 blocks exact
  int j   = idx & 7;
  int ln  = (idx >> 3) & 63;
  int rest= idx >> 9;
  int cb  = rest & 15;
  int rest2 = rest >> 4;
  int ks  = rest2 & 3;
  int l   = rest2 >> 2;
  int k = ks*32 + (ln>>4)*8 + j;
  int c = cb*16 + (ln&15);
  float v = (c < 128) ? cw1[(size_t)l*33152 + (size_t)k*128 + c]
                      : cw1[(size_t)l*33152 + (size_t)(128+k)*128 + (c-128)];
  w1p[idx] = (_Float16)v;
}
// w2p[l][ks][cb(8)][ln][j]; 6*4*8*64*8 = 98304 halfs
__global__ __launch_bounds__(256) void pack_w2p_kernel(const float* __restrict__ cw2,
                                                       _Float16* __restrict__ w2p){
  int idx = blockIdx.x*256 + threadIdx.x;   // 384 blocks exact
  int j   = idx & 7;
  int ln  = (idx >> 3) & 63;
  int rest= idx >> 9;
  int cb  = rest & 7;
  int rest2 = rest >> 3;
  int ks  = rest2 & 3;
  int l   = rest2 >> 2;
  int k = ks*32 + (ln>>4)*8 + j;
  int c = cb*16 + (ln&15);
  w2p[idx] = (_Float16)cw2[(size_t)l*16384 + (size_t)k*128 + c];
}

// ---------------- CSR build ----------------
__global__ __launch_bounds__(256) void count_kernel(const int* __restrict__ ei, int* __restrict__ cnt){
  int e = blockIdx.x*256 + threadIdx.x;   // EE/256 exact
  bool is64 = ei_is64(ei);
  atomicAdd(&cnt[ei_dst(ei, e, is64)], 1);
}

__global__ __launch_bounds__(1024) void scan_kernel(int* __restrict__ cntcur,
                                                    int* __restrict__ row_start,
                                                    float* __restrict__ invd){
  __shared__ int part[1024];
  const int t = threadIdx.x;
  const int base = t*20;
  int loc[20];
  int sum = 0;
  #pragma unroll
  for (int i=0;i<20;++i){
    int n = base+i;
    int v = (n < NN) ? cntcur[n] : 0;
    loc[i] = sum; sum += v;
  }
  part[t] = sum;
  __syncthreads();
  for (int off=1; off<1024; off<<=1){
    int v = (t >= off) ? part[t-off] : 0;
    __syncthreads();
    part[t] += v;
    __syncthreads();
  }
  int pre = (t > 0) ? part[t-1] : 0;
  #pragma unroll
  for (int i=0;i<20;++i){
    int n = base+i;
    if (n < NN){
      int rs = pre + loc[i];
      int deg = ((i<19)?loc[i+1]:sum) - loc[i];
      row_start[n] = rs;
      invd[n] = (deg > 0) ? 1.f/(float)deg : 0.f;
      cntcur[n] = rs;
    }
  }
  if (t == 1023) row_start[NN] = part[1023];
}

__global__ __launch_bounds__(256) void scatter_kernel(const int* __restrict__ ei,
                                                      const float* __restrict__ eattr,
                                                      int* __restrict__ cur,
                                                      int* __restrict__ src_s,
                                                      _Float16* __restrict__ ea_s){
  int e = blockIdx.x*256 + threadIdx.x;   // EE/256 exact
  bool is64 = ei_is64(ei);
  int s = ei_src(ei, e, is64);
  int d = ei_dst(ei, e, is64);
  int pos = atomicAdd(&cur[d], 1);
  src_s[pos] = s;
  half4 ea;
  ea[0] = (_Float16)eattr[(size_t)e*3+0];
  ea[1] = (_Float16)eattr[(size_t)e*3+1];
  ea[2] = (_Float16)eattr[(size_t)e*3+2];
  ea[3] = (_Float16)0.f;
  *(half4*)(ea_s + (size_t)pos*4) = ea;
}

// ---------------- encoder: x(N,14) -> h(N,128) fp32 + hh fp16 ----------------
__global__ __launch_bounds__(128) void encoder_kernel(
    const float* __restrict__ x, const float* __restrict__ w1, const float* __restrict__ b1,
    const float* __restrict__ w2, const float* __restrict__ b2,
    float* __restrict__ h, _Float16* __restrict__ hh)
{
  __shared__ float xs[16][14];
  __shared__ float s1[16][128];
  const int n0 = blockIdx.x*16;
  const int tid = threadIdx.x;
  for (int idx=tid; idx<224; idx+=128){
    int i = idx/14, k = idx%14;
    xs[i][k] = x[(size_t)(n0+i)*14 + k];
  }
  __syncthreads();
  const int o = tid;
  float acc[16];
  float bv = b1[o];
  #pragma unroll
  for (int i=0;i<16;++i) acc[i] = bv;
  for (int k=0;k<14;++k){
    float w = w1[k*128+o];
    #pragma unroll
    for (int i=0;i<16;++i) acc[i] += xs[i][k]*w;
  }
  #pragma unroll
  for (int i=0;i<16;++i) s1[i][o] = silu_f(acc[i]);
  __syncthreads();
  float bv2 = b2[o];
  #pragma unroll
  for (int i=0;i<16;++i) acc[i] = bv2;
  for (int k=0;k<128;k+=4){
    float w0=w2[(k+0)*128+o], w1v=w2[(k+1)*128+o], w2v=w2[(k+2)*128+o], w3v=w2[(k+3)*128+o];
    #pragma unroll
    for (int i=0;i<16;++i){
      float4 sv = *(const float4*)&s1[i][k];
      acc[i] += sv.x*w0 + sv.y*w1v + sv.z*w2v + sv.w*w3v;
    }
  }
  #pragma unroll
  for (int i=0;i<16;++i){
    size_t off = (size_t)(n0+i)*HD + o;
    h[off] = acc[i];
    hh[off] = (_Float16)acc[i];
  }
}

// ---------------- proj (MFMA): UV(N,256) = [hh·W1d + b1 | hh·W1s] fp16 ----------------
// wave = 16 nodes x 256 cols, K=128 (4 ks x 16 cb). 4 waves/block.
__global__ __launch_bounds__(256) void proj_kernel(
    const _Float16* __restrict__ hh, const _Float16* __restrict__ w1p,
    const float* __restrict__ b1, _Float16* __restrict__ UV)
{
  const int tid = threadIdx.x;
  const int wv  = tid >> 6;
  const int ln  = tid & 63;
  const int q   = ln >> 4;
  const int m   = ln & 15;
  const int n0  = (blockIdx.x*4 + wv)*16;
  if (n0 >= NN) return;

  floatx4 acc[16];
  #pragma unroll
  for (int cb=0;cb<16;++cb) acc[cb] = (floatx4){0.f,0.f,0.f,0.f};

  #pragma unroll
  for (int ks=0; ks<4; ++ks){
    half8 a = *(const half8*)(hh + (size_t)(n0+m)*HD + ks*32 + q*8);
    const _Float16* wb = w1p + (size_t)(ks*16*64 + ln)*8;
    #pragma unroll
    for (int cb=0; cb<16; ++cb){
      half8 b = *(const half8*)(wb + (size_t)cb*512);
      acc[cb] = __builtin_amdgcn_mfma_f32_16x16x32_f16(a, b, acc[cb], 0,0,0);
    }
  }
  // epilogue: C col = cb*16+m, row = n0 + q*4 + r
  #pragma unroll
  for (int cb=0; cb<16; ++cb){
    const int c = cb*16 + m;
    const float bias = (c < 128) ? b1[c] : 0.f;
    #pragma unroll
    for (int r=0;r<4;++r)
      UV[(size_t)(n0+q*4+r)*256 + c] = (_Float16)(acc[cb][r] + bias);
  }
}

// ---------------- edge_agg: per-node mean of silu(U[n] + V[src] + ea·W1e) ----------------
__global__ __launch_bounds__(256) void edge_agg_kernel(
    const _Float16* __restrict__ UV, const int* __restrict__ row_start,
    const int* __restrict__ src_s, const _Float16* __restrict__ ea_s,
    const float* __restrict__ w1e,      // conv_w1 + l*33152 + 32768 (3 rows x 128)
    const float* __restrict__ invd, _Float16* __restrict__ S)
{
  const int tid = threadIdx.x;
  const int wv  = __builtin_amdgcn_readfirstlane(tid >> 6);
  const int ln  = tid & 63;
  const int n   = blockIdx.x*4 + wv;   // grid NN/4 = 5000 exact
  const int c0  = ln*2;

  const float2 wc0 = *(const float2*)(w1e +   0 + c0);
  const float2 wc1 = *(const float2*)(w1e + 128 + c0);
  const float2 wc2 = *(const float2*)(w1e + 256 + c0);

  half2v uvp = *(const half2v*)(UV + (size_t)n*256 + c0);
  const float u0 = (float)uvp[0], u1 = (float)uvp[1];

  const int rs = row_start[n], re = row_start[n+1];
  float a0 = 0.f, a1 = 0.f;
  if (re > rs){
    int s = src_s[rs];
    half4 ea = *(const half4*)(ea_s + (size_t)rs*4);
    half2v v = *(const half2v*)(UV + (size_t)s*256 + 128 + c0);
    for (int e = rs+1; e <= re; ++e){
      int s2 = 0; half4 ea2 = {}; half2v v2 = {};
      if (e < re){                     // prefetch next edge
        s2  = src_s[e];
        ea2 = *(const half4*)(ea_s + (size_t)e*4);
        v2  = *(const half2v*)(UV + (size_t)s2*256 + 128 + c0);
      }
      const float e0 = (float)ea[0], e1 = (float)ea[1], e2 = (float)ea[2];
      float p0 = u0 + (float)v[0] + e0*wc0.x + e1*wc1.x + e2*wc2.x;
      float p1 = u1 + (float)v[1] + e0*wc0.y + e1*wc1.y + e2*wc2.y;
      a0 += silu_f(p0);
      a1 += silu_f(p1);
      s = s2; ea = ea2; v = v2;
    }
  }
  const float iv = invd[n];
  half2v outv; outv[0] = (_Float16)(a0*iv); outv[1] = (_Float16)(a1*iv);
  *(half2v*)(S + (size_t)n*HD + c0) = outv;
}

// ---------------- node (MFMA): h += S·W2 + gate·b2 ; refresh hh ----------------
// wave = 16 nodes x 128 cols, K=128 (4 ks x 8 cb). 4 waves/block.
__global__ __launch_bounds__(256) void node_kernel(
    const _Float16* __restrict__ S, const _Float16* __restrict__ w2p,
    const float* __restrict__ b2, const float* __restrict__ invd,
    float* __restrict__ h, _Float16* __restrict__ hh)
{
  const int tid = threadIdx.x;
  const int wv  = tid >> 6;
  const int ln  = tid & 63;
  const int q   = ln >> 4;
  const int m   = ln & 15;
  const int n0  = (blockIdx.x*4 + wv)*16;
  if (n0 >= NN) return;

  floatx4 acc[8];
  #pragma unroll
  for (int cb=0;cb<8;++cb) acc[cb] = (floatx4){0.f,0.f,0.f,0.f};

  #pragma unroll
  for (int ks=0; ks<4; ++ks){
    half8 a = *(const half8*)(S + (size_t)(n0+m)*HD + ks*32 + q*8);
    const _Float16* wb = w2p + (size_t)(ks*8*64 + ln)*8;
    #pragma unroll
    for (int cb=0; cb<8; ++cb){
      half8 b = *(const half8*)(wb + (size_t)cb*512);
      acc[cb] = __builtin_amdgcn_mfma_f32_16x16x32_f16(a, b, acc[cb], 0,0,0);
    }
  }
  float gate[4];
  #pragma unroll
  for (int r=0;r<4;++r) gate[r] = (invd[n0 + q*4 + r] > 0.f) ? 1.f : 0.f;
  #pragma unroll
  for (int cb=0; cb<8; ++cb){
    const int c = cb*16 + m;
    const float bv = b2[c];
    #pragma unroll
    for (int r=0;r<4;++r){
      size_t off = (size_t)(n0+q*4+r)*HD + c;
      float hv = h[off] + acc[cb][r] + gate[r]*bv;
      h[off] = hv;
      hh[off] = (_Float16)hv;
    }
  }
}

// ---------------- decoder: 128 ->(silu) 128 ->(silu) 64 -> 9 ----------------
__global__ __launch_bounds__(128) void decoder_kernel(
    const float* __restrict__ h,
    const float* __restrict__ w1, const float* __restrict__ b1,
    const float* __restrict__ w2, const float* __restrict__ b2,
    const float* __restrict__ w3, const float* __restrict__ b3,
    float* __restrict__ out)
{
  __shared__ float ht[16][128];
  __shared__ float s1[16][128];
  __shared__ float s2[16][65];   // stride 65: breaks same-bank (k%32) conflicts in final stage
  const int n0 = blockIdx.x*16;
  const int tid = threadIdx.x;
  for (int idx=tid; idx<2048; idx+=128){
    int i = idx>>7, k = idx&127;
    ht[i][k] = h[(size_t)(n0+i)*HD + k];
  }
  __syncthreads();
  {
    const int o = tid;
    float acc[16];
    float bv = b1[o];
    #pragma unroll
    for (int i=0;i<16;++i) acc[i] = bv;
    for (int k=0;k<128;k+=4){
      float w0=w1[(k+0)*128+o], w1v=w1[(k+1)*128+o], w2v=w1[(k+2)*128+o], w3v=w1[(k+3)*128+o];
      #pragma unroll
      for (int i=0;i<16;++i){
        float4 hv = *(const float4*)&ht[i][k];
        acc[i] += hv.x*w0 + hv.y*w1v + hv.z*w2v + hv.w*w3v;
      }
    }
    #pragma unroll
    for (int i=0;i<16;++i) s1[i][o] = silu_f(acc[i]);
  }
  __syncthreads();
  {
    const int o = tid & 63;
    const int hf = tid >> 6;
    float acc[8];
    float bv = b2[o];
    #pragma unroll
    for (int i=0;i<8;++i) acc[i] = bv;
    for (int k=0;k<128;k+=4){
      float w0=w2[(k+0)*64+o], w1v=w2[(k+1)*64+o], w2v=w2[(k+2)*64+o], w3v=w2[(k+3)*64+o];
      #pragma unroll
      for (int i=0;i<8;++i){
        float4 sv = *(const float4*)&s1[hf*8+i][k];
        acc[i] += sv.x*w0 + sv.y*w1v + sv.z*w2v + sv.w*w3v;
      }
    }
    #pragma unroll
    for (int i=0;i<8;++i) s2[hf*8+i][o] = silu_f(acc[i]);
  }
  __syncthreads();
  for (int idx = tid; idx < 144; idx += 128){   // loop, NOT "if" — the r1-r5 bug
    int i = idx/9, oo = idx%9;
    float a = b3[oo];
    #pragma unroll 8
    for (int k=0;k<64;++k) a += s2[i][k]*w3[k*9+oo];
    out[(size_t)(n0+i)*9 + oo] = a;
  }
}

// ---------------- workspace layout (35,389,888 B) ----------------
constexpr size_t OFF_H    = 0;                         // 10,240,000
constexpr size_t OFF_HH   = 10240000;                  //  5,120,000
constexpr size_t OFF_UV   = 15360000;                  // 10,240,000
constexpr size_t OFF_S    = 25600000;                  //  5,120,000 (fp16)
constexpr size_t OFF_INVD = 30720000;                  //     80,000
constexpr size_t OFF_RS   = 30800000;                  //     80,064
constexpr size_t OFF_CUR  = 30880064;                  //     80,000
constexpr size_t OFF_SRC  = 30960064;                  //  1,280,000
constexpr size_t OFF_EA   = 32240064;                  //  2,560,000
constexpr size_t OFF_W1P  = 34800064;                  //    393,216
constexpr size_t OFF_W2P  = 35193280;                  //    196,608
constexpr size_t WS_NEEDED= 35389888;

extern "C" void kernel_launch(void* const* d_in, const int* in_sizes, int n_in,
                              void* d_out, int out_size, void* d_ws, size_t ws_size,
                              hipStream_t stream)
{
  float* out = (float*)d_out;
  const int nout_blk = (out_size + 255)/256;

  static const int EXP_SIZES[17] = {280000,640000,960000,1792,128,16384,128,
                                    198912,768,98304,768,16384,128,8192,64,576,9};
  if (n_in != 17){
    sentinel_kernel<<<nout_blk, 256, 0, stream>>>(out, out_size, 2.0e7f + (float)n_in*1.0e3f);
    return;
  }
  for (int i = 0; i < 17; ++i){
    if (in_sizes[i] != EXP_SIZES[i]){
      int sz = in_sizes[i] < 99999 ? in_sizes[i] : 99999;
      sentinel_kernel<<<nout_blk, 256, 0, stream>>>(out, out_size,
          1.0e7f + (float)i*1.0e5f + (float)sz);
      return;
    }
  }
  if (ws_size < WS_NEEDED){
    sentinel_kernel<<<nout_blk, 256, 0, stream>>>(out, out_size, 1.0e6f);
    return;
  }

  const float* x       = (const float*)d_in[0];
  const int*   ei      = (const int*)  d_in[1];
  const float* eattr   = (const float*)d_in[2];
  const float* enc_w1  = (const float*)d_in[3];
  const float* enc_b1  = (const float*)d_in[4];
  const float* enc_w2  = (const float*)d_in[5];
  const float* enc_b2  = (const float*)d_in[6];
  const float* conv_w1 = (const float*)d_in[7];
  const float* conv_b1 = (const float*)d_in[8];
  const float* conv_w2 = (const float*)d_in[9];
  const float* conv_b2 = (const float*)d_in[10];
  const float* dec_w1  = (const float*)d_in[11];
  const float* dec_b1  = (const float*)d_in[12];
  const float* dec_w2  = (const float*)d_in[13];
  const float* dec_b2  = (const float*)d_in[14];
  const float* dec_w3  = (const float*)d_in[15];
  const float* dec_b3  = (const float*)d_in[16];

  char* ws = (char*)d_ws;
  float*    h     = (float*)   (ws + OFF_H);
  _Float16* hh    = (_Float16*)(ws + OFF_HH);
  _Float16* UV    = (_Float16*)(ws + OFF_UV);
  _Float16* S     = (_Float16*)(ws + OFF_S);
  float*    invd  = (float*)   (ws + OFF_INVD);
  int*      rstart= (int*)     (ws + OFF_RS);
  int*      cur   = (int*)     (ws + OFF_CUR);
  int*      src_s = (int*)     (ws + OFF_SRC);
  _Float16* ea_s  = (_Float16*)(ws + OFF_EA);
  _Float16* w1p   = (_Float16*)(ws + OFF_W1P);
  _Float16* w2p   = (_Float16*)(ws + OFF_W2P);

  hipMemsetAsync(cur, 0, (size_t)NN*sizeof(int), stream);

  pack_w1p_kernel<<<768, 256, 0, stream>>>(conv_w1, w1p);
  pack_w2p_kernel<<<384, 256, 0, stream>>>(conv_w2, w2p);
  count_kernel<<<EE/256, 256, 0, stream>>>(ei, cur);
  scan_kernel<<<1, 1024, 0, stream>>>(cur, rstart, invd);
  scatter_kernel<<<EE/256, 256, 0, stream>>>(ei, eattr, cur, src_s, ea_s);
  encoder_kernel<<<NN/16, 128, 0, stream>>>(x, enc_w1, enc_b1, enc_w2, enc_b2, h, hh);
  for (int l=0; l<6; ++l){
    proj_kernel<<<313, 256, 0, stream>>>(hh, w1p + (size_t)l*32768,
                                         conv_b1 + (size_t)l*128, UV);
    edge_agg_kernel<<<NN/4, 256, 0, stream>>>(UV, rstart, src_s, ea_s,
                                              conv_w1 + (size_t)l*33152 + 32768,
                                              invd, S);
    node_kernel<<<313, 256, 0, stream>>>(S, w2p + (size_t)l*16384,
                                         conv_b2 + (size_t)l*128, invd, h, hh);
  }
  decoder_kernel<<<NN/16, 128, 0, stream>>>(h, dec_w1, dec_b1, dec_w2, dec_b2,
                                            dec_w3, dec_b3, out);
}